// Round 3
// baseline (647.855 us; speedup 1.0000x reference)
//
#include <hip/hip_runtime.h>
#include <hip/hip_bf16.h>

// ---------------------------------------------------------------------------
// GNN layer:
//   hproj   = hidden @ Ws^T                       (200000 x 64)   [rowproj64]
//   hrproj  = rela_embed @ Wr^T                   (401 x 64)      [relproj]
//   hqrproj = rela_embed[q_rel] @ Wqr^T + b       (8 x 64)        [qrproj]
//   ct[b][r][:] = hrproj[r] + hqrproj[b]          (8 x 401 x 64)  [build_ct]
//   per edge e: attn  = hproj[sub] + ct[r_idx][rel]
//               alpha = sigmoid(dot(relu(attn), wa) + wa_b)
//               agg[obj] += alpha * (hidden[sub] + rela_embed[rel])  [atomic]
//   out = agg @ Wh^T  (in place on d_out)
// edge_scatter: 2 edges per wave (lanes 0-31 / 32-63), float2 per lane.
// ---------------------------------------------------------------------------

// dst[r][a] = sum_k src[r][k] * W[a][k];  64x64 W, row tile of 64.
// NOTE: no __restrict__ on src/dst — used in-place for the final projection
// (each block stages its own 64 rows to LDS before overwriting them).
__global__ __launch_bounds__(256) void rowproj64(const float* src,
                                                 const float* __restrict__ W,
                                                 float* dst, int nrows) {
    __shared__ float Wt[64][65];    // Wt[k][a] = W[a][k]  (padded: conflict-free)
    __shared__ float4 Sl[64][16];   // 64 rows x 64 cols as float4
    int tid = threadIdx.x;
    for (int i = tid; i < 4096; i += 256) Wt[i & 63][i >> 6] = W[i];
    long r0 = (long)blockIdx.x * 64;
    const float4* src4 = (const float4*)(src + r0 * 64);
    float4* s4 = (float4*)Sl;
    for (int i = tid; i < 1024; i += 256) s4[i] = src4[i];
    __syncthreads();
    int c = tid & 63;            // output column this thread owns
    int rbase = (tid >> 6) * 16; // 16 rows per thread
    float w[64];
#pragma unroll
    for (int k = 0; k < 64; ++k) w[k] = Wt[k][c];  // stride-1 across lanes: conflict-free
#pragma unroll
    for (int r = 0; r < 16; ++r) {
        float a0 = 0.f, a1 = 0.f, a2 = 0.f, a3 = 0.f;
#pragma unroll
        for (int k4 = 0; k4 < 16; ++k4) {
            float4 s = Sl[rbase + r][k4];  // broadcast read (same addr all lanes)
            a0 += s.x * w[4 * k4 + 0];
            a1 += s.y * w[4 * k4 + 1];
            a2 += s.z * w[4 * k4 + 2];
            a3 += s.w * w[4 * k4 + 3];
        }
        dst[(r0 + rbase + r) * 64 + c] = (a0 + a1) + (a2 + a3);  // coalesced
    }
}

// out[r][a] = dot(rela[r], W[a])   (tiny: 401 x 64)
__global__ void relproj(const float* __restrict__ rela,
                        const float* __restrict__ W,
                        float* __restrict__ out) {
    int r = blockIdx.x, a = threadIdx.x;
    __shared__ float h[64];
    h[a] = rela[r * 64 + a];
    __syncthreads();
    float acc = 0.f;
#pragma unroll
    for (int k = 0; k < 64; ++k) acc += h[k] * W[a * 64 + k];
    out[r * 64 + a] = acc;
}

// out[b][a] = dot(rela[q_rel[b]], Wqr[a]) + bqr[a]   (8 x 64)
__global__ void qrproj(const float* __restrict__ rela,
                       const int* __restrict__ q_rel,
                       const float* __restrict__ Wqr,
                       const float* __restrict__ bqr,
                       float* __restrict__ out) {
    int b = blockIdx.x, a = threadIdx.x;
    int qr = q_rel[b];
    __shared__ float h[64];
    h[a] = rela[qr * 64 + a];
    __syncthreads();
    float acc = bqr[a];
#pragma unroll
    for (int k = 0; k < 64; ++k) acc += h[k] * Wqr[a * 64 + k];
    out[b * 64 + a] = acc;
}

// ct[(b*n_rel_tot + r)*64 + a] = hrproj[r][a] + hqrproj[b][a]
__global__ void build_ct(const float* __restrict__ hrproj,
                         const float* __restrict__ hqrproj,
                         float* __restrict__ ct, int n_rel_tot) {
    int idx = blockIdx.x;        // b * n_rel_tot + r
    int a = threadIdx.x;
    int b = idx / n_rel_tot, r = idx - b * n_rel_tot;
    ct[(size_t)idx * 64 + a] = hrproj[r * 64 + a] + hqrproj[b * 64 + a];
}

// 2 edges per wave: lanes 0-31 handle edge 2p, lanes 32-63 handle edge 2p+1.
// Each lane covers 2 features (float2, 8 B). Edge records stay wave-uniform
// (p is readfirstlane'd) -> scalar s_load for both records.
__global__ __launch_bounds__(256) void edge_scatter(
    const int* __restrict__ edges, int E,
    const float* __restrict__ hidden,
    const float* __restrict__ rela,
    const float* __restrict__ hproj,
    const float* __restrict__ ct, int n_rel_tot,
    const float* __restrict__ wa,
    const float* __restrict__ wab_p,
    float* __restrict__ agg) {
    int lane = threadIdx.x & 63;
    int half = lane >> 5;        // which edge of the pair this lane works on
    int li   = lane & 31;        // lane within the half; features {2li, 2li+1}
    int gw = __builtin_amdgcn_readfirstlane(
        (int)((blockIdx.x * blockDim.x + threadIdx.x) >> 6));
    int nw = (int)((gridDim.x * blockDim.x) >> 6);

    const float2* hidden2 = (const float2*)hidden;
    const float2* rela2   = (const float2*)rela;
    const float2* hproj2  = (const float2*)hproj;
    const float2* ct2     = (const float2*)ct;
    float2 wav = ((const float2*)wa)[li];
    float wab = wab_p[0];

    for (int p = gw; 2 * p < E; p += nw) {
        int e0 = 2 * p;
        int e1 = e0 + 1;
        bool v1 = e1 < E;
        const int* ed0 = edges + (size_t)e0 * 6;          // SGPR addr -> s_load
        const int* ed1 = edges + (size_t)(v1 ? e1 : e0) * 6;
        int r_idx = half ? ed1[0] : ed0[0];
        int rel   = half ? ed1[2] : ed0[2];
        int sub   = half ? ed1[4] : ed0[4];
        int obj   = half ? ed1[5] : ed0[5];

        size_t sb = (size_t)sub * 32 + li;
        float2 hp = hproj2[sb];
        float2 cv = ct2[((size_t)r_idx * n_rel_tot + rel) * 32 + li];
        float t = fmaxf(hp.x + cv.x, 0.f) * wav.x
                + fmaxf(hp.y + cv.y, 0.f) * wav.y;
#pragma unroll
        for (int o = 16; o; o >>= 1) t += __shfl_xor(t, o, 64);  // within 32-half
        float alpha = 1.f / (1.f + __expf(-(t + wab)));

        float2 h = hidden2[sb];
        float2 rl = rela2[(size_t)rel * 32 + li];
        if (!half || v1) {
            float* dst = &agg[((size_t)obj * 32 + li) * 2];
            unsafeAtomicAdd(dst + 0, alpha * (h.x + rl.x));   // coalesced pairs
            unsafeAtomicAdd(dst + 1, alpha * (h.y + rl.y));
        }
    }
}

extern "C" void kernel_launch(void* const* d_in, const int* in_sizes, int n_in,
                              void* d_out, int out_size, void* d_ws, size_t ws_size,
                              hipStream_t stream) {
    const int* q_rel    = (const int*)d_in[1];
    const float* hidden = (const float*)d_in[2];
    const int* edges    = (const int*)d_in[3];
    const float* rela   = (const float*)d_in[7];
    const float* Ws     = (const float*)d_in[8];
    const float* Wr     = (const float*)d_in[9];
    const float* WqrW   = (const float*)d_in[10];
    const float* Wqrb   = (const float*)d_in[11];
    const float* waW    = (const float*)d_in[12];
    const float* wab    = (const float*)d_in[13];
    const float* Wh     = (const float*)d_in[14];

    int E = in_sizes[3] / 6;            // 1,000,000
    int n_node = in_sizes[4] / 2;       // 200,000
    int n_rel_tot = in_sizes[7] / 64;   // 401
    int B = in_sizes[0];                // 8

    float* agg = (float*)d_out;                        // n_node*64 accumulator
    float* hproj   = (float*)d_ws;                     // n_node*64
    float* hrproj  = hproj + (size_t)n_node * 64;      // n_rel_tot*64
    float* hqrproj = hrproj + (size_t)n_rel_tot * 64;  // B*64
    float* ct      = hqrproj + (size_t)B * 64;         // B*n_rel_tot*64

    hipMemsetAsync(d_out, 0, (size_t)out_size * sizeof(float), stream);
    rowproj64<<<n_node / 64, 256, 0, stream>>>(hidden, Ws, hproj, n_node);
    relproj<<<n_rel_tot, 64, 0, stream>>>(rela, Wr, hrproj);
    qrproj<<<B, 64, 0, stream>>>(rela, q_rel, WqrW, Wqrb, hqrproj);
    build_ct<<<B * n_rel_tot, 64, 0, stream>>>(hrproj, hqrproj, ct, n_rel_tot);
    edge_scatter<<<2048, 256, 0, stream>>>(edges, E, hidden, rela, hproj,
                                           ct, n_rel_tot, waW, wab, agg);
    rowproj64<<<n_node / 64, 256, 0, stream>>>(agg, Wh, agg, n_node);
}